// Round 15
// baseline (2178.151 us; speedup 1.0000x reference)
//
#include <hip/hip_runtime.h>
#include <cmath>

#define DI __device__ __forceinline__

typedef unsigned short u16;
typedef __bf16 bf16x8 __attribute__((ext_vector_type(8)));
typedef float f32x4 __attribute__((ext_vector_type(4)));

static constexpr int Bsz = 2, T = 1024, D = 768, H = 12, FF = 3072, V = 50257, L = 12;
static constexpr int M = Bsz * T;     // 2048 rows
static constexpr int QKVS = 3 * D;    // fused qkv row stride (2304)

DI u16 f2bf(float f) {
  unsigned u = __float_as_uint(f);
  u = (u + 0x7fffu + ((u >> 16) & 1u)) >> 16;
  return (u16)u;
}
DI float bf2f(u16 h) { return __uint_as_float(((unsigned)h) << 16); }

DI void gload_lds16(const void* g, void* l) {
  __builtin_amdgcn_global_load_lds((const __attribute__((address_space(1))) void*)g,
                                   (__attribute__((address_space(3))) void*)l, 16, 0, 0);
}

// ---------------- transpose + convert: src f32 [R][C] -> dst bf16 [C][R] ----------------
__launch_bounds__(256)
__global__ void transpose_cvt(const float* __restrict__ src, u16* __restrict__ dst, int R, int C) {
  __shared__ float tile[32][33];
  const int tx = threadIdx.x, ty = threadIdx.y;
  const int c0 = blockIdx.x * 32, r0 = blockIdx.y * 32;
  src += (size_t)blockIdx.z * R * C;
  dst += (size_t)blockIdx.z * R * C;
#pragma unroll
  for (int i = 0; i < 4; ++i)
    tile[ty + i * 8][tx] = src[(size_t)(r0 + ty + i * 8) * C + c0 + tx];
  __syncthreads();
#pragma unroll
  for (int i = 0; i < 4; ++i)
    dst[(size_t)(c0 + ty + i * 8) * R + r0 + tx] = f2bf(tile[tx][ty + i * 8]);
}

// merged QKVO transpose: z = mat*L + layer, mat in {0=q,1=k,2=v,3=o}
// q/k/v land in the fused [layer][3D][D] weight (rows 0-767=q, 768-1535=k, 1536-2303=v)
__launch_bounds__(256)
__global__ void transpose_qkvo(const float* __restrict__ Wq, const float* __restrict__ Wk,
                               const float* __restrict__ Wv, const float* __restrict__ Wo,
                               u16* __restrict__ wqkvT, u16* __restrict__ woT) {
  __shared__ float tile[32][33];
  const int tx = threadIdx.x, ty = threadIdx.y;
  const int c0 = blockIdx.x * 32, r0 = blockIdx.y * 32;
  const int z = blockIdx.z, mat = z / L, layer = z % L;
  const float* srcs[4] = {Wq, Wk, Wv, Wo};
  const float* src = srcs[mat] + (size_t)layer * D * D;
  u16* dst = (mat < 3) ? wqkvT + (size_t)layer * 3 * D * D + (size_t)mat * D * D
                       : woT + (size_t)layer * D * D;
#pragma unroll
  for (int i = 0; i < 4; ++i)
    tile[ty + i * 8][tx] = src[(size_t)(r0 + ty + i * 8) * D + c0 + tx];
  __syncthreads();
#pragma unroll
  for (int i = 0; i < 4; ++i)
    dst[(size_t)(c0 + ty + i * 8) * D + r0 + tx] = f2bf(tile[tx][ty + i * 8]);
}

// fused qkv bias: out[l][0:768]=bq[l], [768:1536]=bk[l], [1536:2304]=bv[l]
__launch_bounds__(256)
__global__ void fuse_bias(const float* __restrict__ bq, const float* __restrict__ bk,
                          const float* __restrict__ bv, float* __restrict__ out) {
  const int l = blockIdx.y;
  const int j = blockIdx.x * 256 + threadIdx.x;  // < 2304
  float v;
  if (j < 768) v = bq[l * 768 + j];
  else if (j < 1536) v = bk[l * 768 + j - 768];
  else v = bv[l * 768 + j - 1536];
  out[(size_t)l * QKVS + j] = v;
}

// ---------------- plain convert f32 -> bf16 (tok_emb) ----------------
__global__ void convert_bf16(const float* __restrict__ src, u16* __restrict__ dst, long n4) {
  long i = (long)blockIdx.x * blockDim.x + threadIdx.x;
  long stride = (long)gridDim.x * blockDim.x;
  for (; i < n4; i += stride) {
    float4 f = ((const float4*)src)[i];
    ushort4 o;
    o.x = f2bf(f.x); o.y = f2bf(f.y); o.z = f2bf(f.z); o.w = f2bf(f.w);
    ((ushort4*)dst)[i] = o;
  }
}

// ---------------- embedding: h = tok_emb[x] + pos_emb ----------------
__launch_bounds__(256)
__global__ void embed_kernel(const int* __restrict__ x, const float* __restrict__ tok,
                             const float* __restrict__ pos, float* __restrict__ h) {
  const int row = blockIdx.x, t = threadIdx.x;
  const int tt = row % T;
  const int id = x[row];
  float* o = h + (size_t)row * D;
  const float* te = tok + (size_t)id * D;
  const float* pe = pos + (size_t)tt * D;
  o[t] = te[t] + pe[t];
  o[t + 256] = te[t + 256] + pe[t + 256];
  o[t + 512] = te[t + 512] + pe[t + 512];
}

// ---------------- LayerNorm (biased var), f32 in -> bf16 out, wave-per-row ----------------
__launch_bounds__(256)
__global__ void layernorm_kernel(const float* __restrict__ in, const float* __restrict__ gw,
                                 const float* __restrict__ bw, u16* __restrict__ out) {
  const int lane = threadIdx.x & 63, wid = threadIdx.x >> 6;
  const int row = blockIdx.x * 4 + wid;
  const float4* x4 = (const float4*)(in + (size_t)row * D);
  float4 v[3];
  float sum = 0.f, sq = 0.f;
#pragma unroll
  for (int j = 0; j < 3; ++j) {
    v[j] = x4[lane + 64 * j];
    sum += v[j].x + v[j].y + v[j].z + v[j].w;
    sq += v[j].x * v[j].x + v[j].y * v[j].y + v[j].z * v[j].z + v[j].w * v[j].w;
  }
#pragma unroll
  for (int off = 1; off < 64; off <<= 1) {
    sum += __shfl_xor(sum, off);
    sq += __shfl_xor(sq, off);
  }
  const float mean = sum * (1.0f / D);
  const float var = sq * (1.0f / D) - mean * mean;
  const float rstd = rsqrtf(var + 1e-5f);
  const float4* g4 = (const float4*)gw;
  const float4* b4 = (const float4*)bw;
  ushort4* o4 = (ushort4*)(out + (size_t)row * D);
#pragma unroll
  for (int j = 0; j < 3; ++j) {
    float4 g = g4[lane + 64 * j], b = b4[lane + 64 * j];
    ushort4 o;
    o.x = f2bf((v[j].x - mean) * rstd * g.x + b.x);
    o.y = f2bf((v[j].y - mean) * rstd * g.y + b.y);
    o.z = f2bf((v[j].z - mean) * rstd * g.z + b.z);
    o.w = f2bf((v[j].w - mean) * rstd * g.w + b.w);
    o4[lane + 64 * j] = o;
  }
}

// ---------------- epilogue helper ----------------
template <int EPI>
DI void epilogue_store(float v, size_t idx, float* outF, u16* outH, const float* resid) {
  if (EPI == 0) {
    outH[idx] = f2bf(v);
  } else if (EPI == 1) {
    float ge = 0.5f * v * (1.0f + erff(v * 0.70710678118f));
    outH[idx] = f2bf(ge);
  } else if (EPI == 2) {
    outF[idx] = resid[idx] + v;
  } else {
    // streaming output (logits), never re-read: nontemporal store bypasses L2
    // write-allocation so it can't evict the B-panels the XCD chunk is re-reading.
    __builtin_nontemporal_store(v, &outF[idx]);
  }
}

// ---------------- NT bf16 GEMM core (single-buffer m97 structure) ----------------
// 4 waves in 2x2; wave tile (BM/2)x(BN/2); chunk-XOR LDS swizzle on stage-src + read.
// EPI: 0 bf16 (+bias); 1 exact GELU -> bf16 (+bias); 2 f32 resid add; 3 f32 nt-store;
//      4 bf16 (+bias) with cols<D scaled by 0.125 (fused qkv q-prescale).
template <int EPI, int BM, int BN, int BK>
DI void gemm_core(const u16* __restrict__ A, const u16* __restrict__ Bt,
                  const float* bias, float* outF, u16* outH, const float* resid,
                  int N, int K, int m0, int n0) {
  __shared__ u16 sA[BM * BK];
  __shared__ u16 sB[BN * BK];
  constexpr int FM = BM / 32, FN = BN / 32;
  constexpr int CPR = BK / 8;
  constexpr int KS = BK / 32;
  constexpr int AI = BM * BK / 8 / 256;
  constexpr int BI = BN * BK / 8 / 256;
  const int t = threadIdx.x;
  const int lane = t & 63, wid = t >> 6;

  f32x4 acc[FM][FN] = {};
  const int wr = (wid >> 1) * (BM / 2), wc = (wid & 1) * (BN / 2);
  const int rsel = lane & 15, ksel = lane >> 4;

  for (int k0 = 0; k0 < K; k0 += BK) {
#pragma unroll
    for (int i = 0; i < AI; ++i) {
      int c = t + i * 256;
      int row = c / CPR, ch = c % CPR;
      int g = ch ^ (row & (CPR - 1));
      gload_lds16(A + (size_t)(m0 + row) * K + k0 + g * 8, &sA[c * 8]);
    }
#pragma unroll
    for (int i = 0; i < BI; ++i) {
      int c = t + i * 256;
      int row = c / CPR, ch = c % CPR;
      int g = ch ^ (row & (CPR - 1));
      int nr = n0 + row;
      if (nr >= N) nr = N - 1;  // tail: duplicate row, stores are guarded
      gload_lds16(Bt + (size_t)nr * K + k0 + g * 8, &sB[c * 8]);
    }
    __syncthreads();
#pragma unroll
    for (int ks = 0; ks < KS; ++ks) {
      bf16x8 af[FM], bfr[FN];
#pragma unroll
      for (int m = 0; m < FM; ++m) {
        int row = wr + m * 16 + rsel;
        int ch = (ksel + 4 * ks) ^ (row & (CPR - 1));
        af[m] = *(const bf16x8*)&sA[row * BK + ch * 8];
      }
#pragma unroll
      for (int n = 0; n < FN; ++n) {
        int row = wc + n * 16 + rsel;
        int ch = (ksel + 4 * ks) ^ (row & (CPR - 1));
        bfr[n] = *(const bf16x8*)&sB[row * BK + ch * 8];
      }
#pragma unroll
      for (int m = 0; m < FM; ++m)
#pragma unroll
        for (int n = 0; n < FN; ++n)
          acc[m][n] = __builtin_amdgcn_mfma_f32_16x16x32_bf16(af[m], bfr[n], acc[m][n], 0, 0, 0);
    }
    __syncthreads();
  }

  const int rq = lane >> 4;
#pragma unroll
  for (int m = 0; m < FM; ++m) {
#pragma unroll
    for (int n = 0; n < FN; ++n) {
      const int col = n0 + wc + n * 16 + rsel;
      if (col >= N) continue;
      const float bv = bias ? bias[col] : 0.0f;
#pragma unroll
      for (int i = 0; i < 4; ++i) {
        const int row = m0 + wr + m * 16 + rq * 4 + i;
        float v = acc[m][n][i] + bv;
        if (EPI == 4 && col < D) v *= 0.125f;  // fold softmax scale into q (exact pow-2)
        epilogue_store<EPI == 4 ? 0 : EPI>(v, (size_t)row * N + col, outF, outH, resid);
      }
    }
  }
}

// distinct names per role; layer GEMMs use PLAIN blockIdx (L2-resident working sets:
// XCD swizzle measured -87us on these in R13 -- T1 only pays when HBM-bound, i.e. lm).
__launch_bounds__(256) __global__ void gemm_qkv(const u16* __restrict__ A, const u16* __restrict__ Bt,
                                                const float* bias, u16* out) {
  gemm_core<4, 128, 64, 64>(A, Bt, bias, nullptr, out, nullptr, QKVS, D,
                            blockIdx.x * 128, blockIdx.y * 64);
}
__launch_bounds__(256) __global__ void gemm_proj(const u16* __restrict__ A, const u16* __restrict__ Bt,
                                                 const float* bias, float* h) {
  gemm_core<2, 64, 64, 64>(A, Bt, bias, h, nullptr, h, D, D,
                           blockIdx.x * 64, blockIdx.y * 64);
}
__launch_bounds__(256) __global__ void gemm_ff1(const u16* __restrict__ A, const u16* __restrict__ Bt,
                                                const float* bias, u16* out) {
  gemm_core<1, 128, 64, 64>(A, Bt, bias, nullptr, out, nullptr, FF, D,
                            blockIdx.x * 128, blockIdx.y * 64);
}
__launch_bounds__(256) __global__ void gemm_ff2(const u16* __restrict__ A, const u16* __restrict__ Bt,
                                                const float* bias, float* h) {
  gemm_core<2, 64, 64, 128>(A, Bt, bias, h, nullptr, h, D, FF,
                            blockIdx.x * 64, blockIdx.y * 64);
}
// LM head: 128x128 tile, BK=32 (best measured config), bijective XCD-chunk swizzle.
__launch_bounds__(256) __global__ void gemm_lm(const u16* __restrict__ A, const u16* __restrict__ Bt,
                                               float* out) {
  const int flat = blockIdx.y * gridDim.x + blockIdx.x;
  const int nwg = gridDim.x * gridDim.y;  // 16*393, %8==0
  const int cpx = nwg >> 3;
  const int nf = (flat & 7) * cpx + (flat >> 3);
  const int m0 = (nf & 15) * 128, n0 = (nf >> 4) * 128;
  gemm_core<3, 128, 128, 32>(A, Bt, nullptr, out, nullptr, nullptr, V, D, m0, n0);
}

// ---------------- MFMA causal flash attention, 64 q-rows/block ----------------
// 4 waves x 16 q-rows, one (b,h); 64-key tiles; heavy q-chunks dispatch first.
// q arrives pre-scaled by 1/8 (qkv epilogue); masking only on the diagonal tile.
// s_setprio(1) around MFMA clusters (T5, attn-proven).
__launch_bounds__(256)
__global__ void attn_mfma(const u16* __restrict__ qkv, u16* __restrict__ ctx) {
  __shared__ u16 sK[64 * 64];
  __shared__ u16 sVT[64 * 72];
  __shared__ u16 sP[4][16 * 72];
  const int t = threadIdx.x, lane = t & 63, wid = t >> 6;
  const int l15 = lane & 15, g = lane >> 4;
  const int qc = gridDim.x - 1 - blockIdx.x;  // reversed: longest blocks first
  const int q0 = qc * 64;
  const int bh = blockIdx.y;
  const int b = bh / H, hh = bh % H;
  const size_t rowbase = (size_t)b * T;
  u16* sPw = &sP[wid][0];

  const size_t qoff = (rowbase + q0 + wid * 16 + l15) * QKVS + hh * 64 + g * 8;
  bf16x8 aQ0 = *(const bf16x8*)&qkv[qoff];
  bf16x8 aQ1 = *(const bf16x8*)&qkv[qoff + 32];

  float mr[4] = {-INFINITY, -INFINITY, -INFINITY, -INFINITY};
  float lr[4] = {0.f, 0.f, 0.f, 0.f};
  f32x4 o[4] = {};
  const int nt = qc + 1;

  for (int kt = 0; kt < nt; ++kt) {
    __syncthreads();  // prior-tile reads done before overwrite
#pragma unroll
    for (int i = 0; i < 2; ++i) {  // stage K: linear dest, pre-swizzled source (rule 21)
      int c = t + i * 256;
      int row = c >> 3, ch = c & 7;
      gload_lds16(qkv + (rowbase + kt * 64 + row) * QKVS + D + hh * 64 +
                      (size_t)((ch ^ (row & 7)) * 8),
                  &sK[c * 8]);
    }
    {  // stage V transposed via ushort2 pairs: thread = (key pair a, dim group d0)
      const int a = t & 31, d0 = (t >> 5) * 8;
      const size_t vrow = (rowbase + kt * 64 + 2 * a) * QKVS + 2 * D + hh * 64 + d0;
      bf16x8 vA = *(const bf16x8*)&qkv[vrow];
      bf16x8 vB = *(const bf16x8*)&qkv[vrow + QKVS];
#pragma unroll
      for (int j = 0; j < 8; ++j) {
        ushort2 w;
        w.x = ((u16*)&vA)[j];
        w.y = ((u16*)&vB)[j];
        *(ushort2*)&sVT[(d0 + j) * 72 + 2 * a] = w;
      }
    }
    __syncthreads();

    // QK^T: S[16q][64k] = 4 key-frags x 2 mfma
    f32x4 s[4];
    __builtin_amdgcn_s_setprio(1);
#pragma unroll
    for (int f = 0; f < 4; ++f) {
      const int krow = f * 16 + l15;
      bf16x8 bk0 = *(const bf16x8*)&sK[krow * 64 + ((g ^ (krow & 7)) * 8)];
      bf16x8 bk1 = *(const bf16x8*)&sK[krow * 64 + (((g + 4) ^ (krow & 7)) * 8)];
      f32x4 z = {};
      z = __builtin_amdgcn_mfma_f32_16x16x32_bf16(aQ0, bk0, z, 0, 0, 0);
      s[f] = __builtin_amdgcn_mfma_f32_16x16x32_bf16(aQ1, bk1, z, 0, 0, 0);
    }
    __builtin_amdgcn_s_setprio(0);

    // online softmax per q-row (rows in (g,i); keys in (f,l15))
    float p[4][4], scl[4];
    const bool diag = (kt == qc);  // only the diagonal tile needs causal masking
#pragma unroll
    for (int i = 0; i < 4; ++i) {
      float v0 = s[0][i], v1 = s[1][i], v2 = s[2][i], v3 = s[3][i];
      if (diag) {
        const int qrow = q0 + wid * 16 + g * 4 + i;
        const int kb = kt * 64 + l15;
        v0 = (kb <= qrow) ? v0 : -INFINITY;
        v1 = (kb + 16 <= qrow) ? v1 : -INFINITY;
        v2 = (kb + 32 <= qrow) ? v2 : -INFINITY;
        v3 = (kb + 48 <= qrow) ? v3 : -INFINITY;
      }
      float mt = fmaxf(fmaxf(v0, v1), fmaxf(v2, v3));
#pragma unroll
      for (int off = 1; off < 16; off <<= 1) mt = fmaxf(mt, __shfl_xor(mt, off));
      const float mn = fmaxf(mr[i], mt);
      const float sc = __expf(mr[i] - mn);
      p[0][i] = __expf(v0 - mn); p[1][i] = __expf(v1 - mn);
      p[2][i] = __expf(v2 - mn); p[3][i] = __expf(v3 - mn);
      float rs = p[0][i] + p[1][i] + p[2][i] + p[3][i];
#pragma unroll
      for (int off = 1; off < 16; off <<= 1) rs += __shfl_xor(rs, off);
      lr[i] = lr[i] * sc + rs;
      mr[i] = mn;
      scl[i] = sc;
    }
#pragma unroll
    for (int n = 0; n < 4; ++n) {
      o[n][0] *= scl[0]; o[n][1] *= scl[1]; o[n][2] *= scl[2]; o[n][3] *= scl[3];
    }
#pragma unroll
    for (int f = 0; f < 4; ++f)  // P -> per-wave LDS (C-layout scatter, A-layout gather)
#pragma unroll
      for (int i = 0; i < 4; ++i)
        sPw[(g * 4 + i) * 72 + f * 16 + l15] = f2bf(p[f][i]);

    // PV: O[16q][64d] += P[16q][64k] V[64k][64d]
    __builtin_amdgcn_s_setprio(1);
#pragma unroll
    for (int kb = 0; kb < 2; ++kb) {
      bf16x8 pa = *(const bf16x8*)&sPw[l15 * 72 + kb * 32 + g * 8];
#pragma unroll
      for (int n = 0; n < 4; ++n) {
        bf16x8 bv = *(const bf16x8*)&sVT[(n * 16 + l15) * 72 + kb * 32 + g * 8];
        o[n] = __builtin_amdgcn_mfma_f32_16x16x32_bf16(pa, bv, o[n], 0, 0, 0);
      }
    }
    __builtin_amdgcn_s_setprio(0);
  }

  float inv[4] = {1.0f / lr[0], 1.0f / lr[1], 1.0f / lr[2], 1.0f / lr[3]};
#pragma unroll
  for (int n = 0; n < 4; ++n)
#pragma unroll
    for (int i = 0; i < 4; ++i)
      ctx[(rowbase + q0 + wid * 16 + g * 4 + i) * D + hh * 64 + n * 16 + l15] =
          f2bf(o[n][i] * inv[i]);
}

// ---------------- host orchestration ----------------
extern "C" void kernel_launch(void* const* d_in, const int* in_sizes, int n_in,
                              void* d_out, int out_size, void* d_ws, size_t ws_size,
                              hipStream_t stream) {
  (void)in_sizes; (void)n_in; (void)out_size;
  const int* x = (const int*)d_in[0];
  const float* tok = (const float*)d_in[1];
  const float* pos = (const float*)d_in[2];
  const float* Wq = (const float*)d_in[3];
  const float* bq = (const float*)d_in[4];
  const float* Wk = (const float*)d_in[5];
  const float* bk = (const float*)d_in[6];
  const float* Wv = (const float*)d_in[7];
  const float* bv = (const float*)d_in[8];
  const float* Wo = (const float*)d_in[9];
  const float* bo = (const float*)d_in[10];
  const float* ln1_g = (const float*)d_in[11];
  const float* ln1_b = (const float*)d_in[12];
  const float* ln2_g = (const float*)d_in[13];
  const float* ln2_b = (const float*)d_in[14];
  const float* W1 = (const float*)d_in[15];
  const float* b1 = (const float*)d_in[16];
  const float* W2 = (const float*)d_in[17];
  const float* b2 = (const float*)d_in[18];
  const float* lnf_g = (const float*)d_in[19];
  const float* lnf_b = (const float*)d_in[20];

  char* ws = (char*)d_ws;
  size_t off = 0;
  auto alloc = [&](size_t bytes) {
    void* p = ws + off;
    off += (bytes + 255) & ~(size_t)255;
    return p;
  };
  u16* wqkvT = (u16*)alloc((size_t)L * 3 * D * D * 2);  // [layer][3D][D] fused
  u16* woT   = (u16*)alloc((size_t)L * D * D * 2);
  u16* w1T   = (u16*)alloc((size_t)L * D * FF * 2);     // [layer][FF][D]
  u16* w2T   = (u16*)alloc((size_t)L * FF * D * 2);     // [layer][D][FF]
  u16* tokT  = (u16*)alloc((size_t)V * D * 2);
  float* bQKV = (float*)alloc((size_t)L * QKVS * 4);    // fused qkv bias
  float* h   = (float*)alloc((size_t)M * D * 4);
  u16* x2    = (u16*)alloc((size_t)M * D * 2);
  u16* qkv   = (u16*)alloc((size_t)M * QKVS * 2);
  u16* ctx   = (u16*)alloc((size_t)M * D * 2);
  u16* ffb   = (u16*)alloc((size_t)M * FF * 2);
  u16* hf    = (u16*)alloc((size_t)M * D * 2);
  if (off > ws_size) return;  // insufficient workspace -> loud validation failure

  const dim3 tb(32, 8);
  transpose_qkvo<<<dim3(D / 32, D / 32, 4 * L), tb, 0, stream>>>(Wq, Wk, Wv, Wo, wqkvT, woT);
  transpose_cvt<<<dim3(FF / 32, D / 32, L), tb, 0, stream>>>(W1, w1T, D, FF);
  transpose_cvt<<<dim3(D / 32, FF / 32, L), tb, 0, stream>>>(W2, w2T, FF, D);
  convert_bf16<<<2048, 256, 0, stream>>>(tok, tokT, (long)V * D / 4);
  fuse_bias<<<dim3(QKVS / 256, L), 256, 0, stream>>>(bq, bk, bv, bQKV);

  embed_kernel<<<M, 256, 0, stream>>>(x, tok, pos, h);

  for (int l = 0; l < L; ++l) {
    layernorm_kernel<<<M / 4, 256, 0, stream>>>(h, ln1_g + (size_t)l * D, ln1_b + (size_t)l * D, x2);
    gemm_qkv<<<dim3(M / 128, QKVS / 64), 256, 0, stream>>>(
        x2, wqkvT + (size_t)l * 3 * D * D, bQKV + (size_t)l * QKVS, qkv);
    attn_mfma<<<dim3(T / 64, Bsz * H), 256, 0, stream>>>(qkv, ctx);
    gemm_proj<<<dim3(M / 64, D / 64), 256, 0, stream>>>(ctx, woT + (size_t)l * D * D,
                                                        bo + (size_t)l * D, h);
    layernorm_kernel<<<M / 4, 256, 0, stream>>>(h, ln2_g + (size_t)l * D, ln2_b + (size_t)l * D, x2);
    gemm_ff1<<<dim3(M / 128, FF / 64), 256, 0, stream>>>(x2, w1T + (size_t)l * D * FF,
                                                         b1 + (size_t)l * FF, ffb);
    gemm_ff2<<<dim3(M / 64, D / 64), 256, 0, stream>>>(ffb, w2T + (size_t)l * FF * D,
                                                       b2 + (size_t)l * D, h);
  }

  layernorm_kernel<<<M / 4, 256, 0, stream>>>(h, lnf_g, lnf_b, hf);
  gemm_lm<<<dim3(16, 393), 256, 0, stream>>>(hf, tokT, (float*)d_out);
}

// Round 16
// 2015.637 us; speedup vs baseline: 1.0806x; 1.0806x over previous
//
#include <hip/hip_runtime.h>
#include <cmath>

#define DI __device__ __forceinline__

typedef unsigned short u16;
typedef __bf16 bf16x8 __attribute__((ext_vector_type(8)));
typedef float f32x4 __attribute__((ext_vector_type(4)));

static constexpr int Bsz = 2, T = 1024, D = 768, H = 12, FF = 3072, V = 50257, L = 12;
static constexpr int M = Bsz * T;     // 2048 rows
static constexpr int QKVS = 3 * D;    // fused qkv row stride (2304)

DI u16 f2bf(float f) {
  unsigned u = __float_as_uint(f);
  u = (u + 0x7fffu + ((u >> 16) & 1u)) >> 16;
  return (u16)u;
}
DI float bf2f(u16 h) { return __uint_as_float(((unsigned)h) << 16); }

DI void gload_lds16(const void* g, void* l) {
  __builtin_amdgcn_global_load_lds((const __attribute__((address_space(1))) void*)g,
                                   (__attribute__((address_space(3))) void*)l, 16, 0, 0);
}

// ---------------- transpose + convert: src f32 [R][C] -> dst bf16 [C][R] ----------------
__launch_bounds__(256)
__global__ void transpose_cvt(const float* __restrict__ src, u16* __restrict__ dst, int R, int C) {
  __shared__ float tile[32][33];
  const int tx = threadIdx.x, ty = threadIdx.y;
  const int c0 = blockIdx.x * 32, r0 = blockIdx.y * 32;
  src += (size_t)blockIdx.z * R * C;
  dst += (size_t)blockIdx.z * R * C;
#pragma unroll
  for (int i = 0; i < 4; ++i)
    tile[ty + i * 8][tx] = src[(size_t)(r0 + ty + i * 8) * C + c0 + tx];
  __syncthreads();
#pragma unroll
  for (int i = 0; i < 4; ++i)
    dst[(size_t)(c0 + ty + i * 8) * R + r0 + tx] = f2bf(tile[tx][ty + i * 8]);
}

// merged QKVO transpose: z = mat*L + layer, mat in {0=q,1=k,2=v,3=o}
// q/k/v land in the fused [layer][3D][D] weight (rows 0-767=q, 768-1535=k, 1536-2303=v)
__launch_bounds__(256)
__global__ void transpose_qkvo(const float* __restrict__ Wq, const float* __restrict__ Wk,
                               const float* __restrict__ Wv, const float* __restrict__ Wo,
                               u16* __restrict__ wqkvT, u16* __restrict__ woT) {
  __shared__ float tile[32][33];
  const int tx = threadIdx.x, ty = threadIdx.y;
  const int c0 = blockIdx.x * 32, r0 = blockIdx.y * 32;
  const int z = blockIdx.z, mat = z / L, layer = z % L;
  const float* srcs[4] = {Wq, Wk, Wv, Wo};
  const float* src = srcs[mat] + (size_t)layer * D * D;
  u16* dst = (mat < 3) ? wqkvT + (size_t)layer * 3 * D * D + (size_t)mat * D * D
                       : woT + (size_t)layer * D * D;
#pragma unroll
  for (int i = 0; i < 4; ++i)
    tile[ty + i * 8][tx] = src[(size_t)(r0 + ty + i * 8) * D + c0 + tx];
  __syncthreads();
#pragma unroll
  for (int i = 0; i < 4; ++i)
    dst[(size_t)(c0 + ty + i * 8) * D + r0 + tx] = f2bf(tile[tx][ty + i * 8]);
}

// fused qkv bias: out[l][0:768]=bq[l], [768:1536]=bk[l], [1536:2304]=bv[l]
__launch_bounds__(256)
__global__ void fuse_bias(const float* __restrict__ bq, const float* __restrict__ bk,
                          const float* __restrict__ bv, float* __restrict__ out) {
  const int l = blockIdx.y;
  const int j = blockIdx.x * 256 + threadIdx.x;  // < 2304
  float v;
  if (j < 768) v = bq[l * 768 + j];
  else if (j < 1536) v = bk[l * 768 + j - 768];
  else v = bv[l * 768 + j - 1536];
  out[(size_t)l * QKVS + j] = v;
}

// ---------------- plain convert f32 -> bf16 (tok_emb) ----------------
__global__ void convert_bf16(const float* __restrict__ src, u16* __restrict__ dst, long n4) {
  long i = (long)blockIdx.x * blockDim.x + threadIdx.x;
  long stride = (long)gridDim.x * blockDim.x;
  for (; i < n4; i += stride) {
    float4 f = ((const float4*)src)[i];
    ushort4 o;
    o.x = f2bf(f.x); o.y = f2bf(f.y); o.z = f2bf(f.z); o.w = f2bf(f.w);
    ((ushort4*)dst)[i] = o;
  }
}

// ---------------- embedding: h = tok_emb[x] + pos_emb ----------------
__launch_bounds__(256)
__global__ void embed_kernel(const int* __restrict__ x, const float* __restrict__ tok,
                             const float* __restrict__ pos, float* __restrict__ h) {
  const int row = blockIdx.x, t = threadIdx.x;
  const int tt = row % T;
  const int id = x[row];
  float* o = h + (size_t)row * D;
  const float* te = tok + (size_t)id * D;
  const float* pe = pos + (size_t)tt * D;
  o[t] = te[t] + pe[t];
  o[t + 256] = te[t + 256] + pe[t + 256];
  o[t + 512] = te[t + 512] + pe[t + 512];
}

// ---------------- LayerNorm (biased var), f32 in -> bf16 out, wave-per-row ----------------
__launch_bounds__(256)
__global__ void layernorm_kernel(const float* __restrict__ in, const float* __restrict__ gw,
                                 const float* __restrict__ bw, u16* __restrict__ out) {
  const int lane = threadIdx.x & 63, wid = threadIdx.x >> 6;
  const int row = blockIdx.x * 4 + wid;
  const float4* x4 = (const float4*)(in + (size_t)row * D);
  float4 v[3];
  float sum = 0.f, sq = 0.f;
#pragma unroll
  for (int j = 0; j < 3; ++j) {
    v[j] = x4[lane + 64 * j];
    sum += v[j].x + v[j].y + v[j].z + v[j].w;
    sq += v[j].x * v[j].x + v[j].y * v[j].y + v[j].z * v[j].z + v[j].w * v[j].w;
  }
#pragma unroll
  for (int off = 1; off < 64; off <<= 1) {
    sum += __shfl_xor(sum, off);
    sq += __shfl_xor(sq, off);
  }
  const float mean = sum * (1.0f / D);
  const float var = sq * (1.0f / D) - mean * mean;
  const float rstd = rsqrtf(var + 1e-5f);
  const float4* g4 = (const float4*)gw;
  const float4* b4 = (const float4*)bw;
  ushort4* o4 = (ushort4*)(out + (size_t)row * D);
#pragma unroll
  for (int j = 0; j < 3; ++j) {
    float4 g = g4[lane + 64 * j], b = b4[lane + 64 * j];
    ushort4 o;
    o.x = f2bf((v[j].x - mean) * rstd * g.x + b.x);
    o.y = f2bf((v[j].y - mean) * rstd * g.y + b.y);
    o.z = f2bf((v[j].z - mean) * rstd * g.z + b.z);
    o.w = f2bf((v[j].w - mean) * rstd * g.w + b.w);
    o4[lane + 64 * j] = o;
  }
}

// ---------------- epilogue helper ----------------
template <int EPI>
DI void epilogue_store(float v, size_t idx, float* outF, u16* outH, const float* resid) {
  if (EPI == 0) {
    outH[idx] = f2bf(v);
  } else if (EPI == 1) {
    float ge = 0.5f * v * (1.0f + erff(v * 0.70710678118f));
    outH[idx] = f2bf(ge);
  } else if (EPI == 2) {
    outF[idx] = resid[idx] + v;
  } else {
    // plain cached store: L2 merges the 64B partial-line writes into full lines.
    // (R15 measured: nontemporal here halves FETCH but ~2x WRITE -- net loss.)
    outF[idx] = v;
  }
}

// ---------------- NT bf16 GEMM core (single-buffer m97 structure) ----------------
// 4 waves in 2x2; wave tile (BM/2)x(BN/2); chunk-XOR LDS swizzle on stage-src + read.
// EPI: 0 bf16 (+bias); 1 exact GELU -> bf16 (+bias); 2 f32 resid add; 3 f32 store;
//      4 bf16 (+bias) with cols<D scaled by 0.125 (fused qkv q-prescale).
template <int EPI, int BM, int BN, int BK>
DI void gemm_core(const u16* __restrict__ A, const u16* __restrict__ Bt,
                  const float* bias, float* outF, u16* outH, const float* resid,
                  int N, int K, int m0, int n0) {
  __shared__ u16 sA[BM * BK];
  __shared__ u16 sB[BN * BK];
  constexpr int FM = BM / 32, FN = BN / 32;
  constexpr int CPR = BK / 8;
  constexpr int KS = BK / 32;
  constexpr int AI = BM * BK / 8 / 256;
  constexpr int BI = BN * BK / 8 / 256;
  const int t = threadIdx.x;
  const int lane = t & 63, wid = t >> 6;

  f32x4 acc[FM][FN] = {};
  const int wr = (wid >> 1) * (BM / 2), wc = (wid & 1) * (BN / 2);
  const int rsel = lane & 15, ksel = lane >> 4;

  for (int k0 = 0; k0 < K; k0 += BK) {
#pragma unroll
    for (int i = 0; i < AI; ++i) {
      int c = t + i * 256;
      int row = c / CPR, ch = c % CPR;
      int g = ch ^ (row & (CPR - 1));
      gload_lds16(A + (size_t)(m0 + row) * K + k0 + g * 8, &sA[c * 8]);
    }
#pragma unroll
    for (int i = 0; i < BI; ++i) {
      int c = t + i * 256;
      int row = c / CPR, ch = c % CPR;
      int g = ch ^ (row & (CPR - 1));
      int nr = n0 + row;
      if (nr >= N) nr = N - 1;  // tail: duplicate row, stores are guarded
      gload_lds16(Bt + (size_t)nr * K + k0 + g * 8, &sB[c * 8]);
    }
    __syncthreads();
#pragma unroll
    for (int ks = 0; ks < KS; ++ks) {
      bf16x8 af[FM], bfr[FN];
#pragma unroll
      for (int m = 0; m < FM; ++m) {
        int row = wr + m * 16 + rsel;
        int ch = (ksel + 4 * ks) ^ (row & (CPR - 1));
        af[m] = *(const bf16x8*)&sA[row * BK + ch * 8];
      }
#pragma unroll
      for (int n = 0; n < FN; ++n) {
        int row = wc + n * 16 + rsel;
        int ch = (ksel + 4 * ks) ^ (row & (CPR - 1));
        bfr[n] = *(const bf16x8*)&sB[row * BK + ch * 8];
      }
#pragma unroll
      for (int m = 0; m < FM; ++m)
#pragma unroll
        for (int n = 0; n < FN; ++n)
          acc[m][n] = __builtin_amdgcn_mfma_f32_16x16x32_bf16(af[m], bfr[n], acc[m][n], 0, 0, 0);
    }
    __syncthreads();
  }

  const int rq = lane >> 4;
#pragma unroll
  for (int m = 0; m < FM; ++m) {
#pragma unroll
    for (int n = 0; n < FN; ++n) {
      const int col = n0 + wc + n * 16 + rsel;
      if (col >= N) continue;
      const float bv = bias ? bias[col] : 0.0f;
#pragma unroll
      for (int i = 0; i < 4; ++i) {
        const int row = m0 + wr + m * 16 + rq * 4 + i;
        float v = acc[m][n][i] + bv;
        if (EPI == 4 && col < D) v *= 0.125f;  // fold softmax scale into q (exact pow-2)
        epilogue_store<EPI == 4 ? 0 : EPI>(v, (size_t)row * N + col, outF, outH, resid);
      }
    }
  }
}

// distinct names per role; layer GEMMs use PLAIN blockIdx (L2-resident working sets:
// XCD swizzle measured -87us on these in R13 -- T1 only pays when HBM-bound, i.e. lm).
__launch_bounds__(256) __global__ void gemm_qkv(const u16* __restrict__ A, const u16* __restrict__ Bt,
                                                const float* bias, u16* out) {
  gemm_core<4, 128, 64, 64>(A, Bt, bias, nullptr, out, nullptr, QKVS, D,
                            blockIdx.x * 128, blockIdx.y * 64);
}
__launch_bounds__(256) __global__ void gemm_proj(const u16* __restrict__ A, const u16* __restrict__ Bt,
                                                 const float* bias, float* h) {
  gemm_core<2, 64, 64, 64>(A, Bt, bias, h, nullptr, h, D, D,
                           blockIdx.x * 64, blockIdx.y * 64);
}
__launch_bounds__(256) __global__ void gemm_ff1(const u16* __restrict__ A, const u16* __restrict__ Bt,
                                                const float* bias, u16* out) {
  gemm_core<1, 128, 64, 64>(A, Bt, bias, nullptr, out, nullptr, FF, D,
                            blockIdx.x * 128, blockIdx.y * 64);
}
__launch_bounds__(256) __global__ void gemm_ff2(const u16* __restrict__ A, const u16* __restrict__ Bt,
                                                const float* bias, float* h) {
  gemm_core<2, 64, 64, 128>(A, Bt, bias, h, nullptr, h, D, FF,
                            blockIdx.x * 64, blockIdx.y * 64);
}
// LM head: 128x128 tile, BK=32 (best measured config), bijective XCD-chunk swizzle.
__launch_bounds__(256) __global__ void gemm_lm(const u16* __restrict__ A, const u16* __restrict__ Bt,
                                               float* out) {
  const int flat = blockIdx.y * gridDim.x + blockIdx.x;
  const int nwg = gridDim.x * gridDim.y;  // 16*393, %8==0
  const int cpx = nwg >> 3;
  const int nf = (flat & 7) * cpx + (flat >> 3);
  const int m0 = (nf & 15) * 128, n0 = (nf >> 4) * 128;
  gemm_core<3, 128, 128, 32>(A, Bt, nullptr, out, nullptr, nullptr, V, D, m0, n0);
}

// ---------------- MFMA causal flash attention, 64 q-rows/block ----------------
// 4 waves x 16 q-rows, one (b,h); 64-key tiles; heavy q-chunks dispatch first.
// q arrives pre-scaled by 1/8 (qkv epilogue); masking only on the diagonal tile.
// s_setprio(1) around MFMA clusters (T5, attn-proven).
__launch_bounds__(256)
__global__ void attn_mfma(const u16* __restrict__ qkv, u16* __restrict__ ctx) {
  __shared__ u16 sK[64 * 64];
  __shared__ u16 sVT[64 * 72];
  __shared__ u16 sP[4][16 * 72];
  const int t = threadIdx.x, lane = t & 63, wid = t >> 6;
  const int l15 = lane & 15, g = lane >> 4;
  const int qc = gridDim.x - 1 - blockIdx.x;  // reversed: longest blocks first
  const int q0 = qc * 64;
  const int bh = blockIdx.y;
  const int b = bh / H, hh = bh % H;
  const size_t rowbase = (size_t)b * T;
  u16* sPw = &sP[wid][0];

  const size_t qoff = (rowbase + q0 + wid * 16 + l15) * QKVS + hh * 64 + g * 8;
  bf16x8 aQ0 = *(const bf16x8*)&qkv[qoff];
  bf16x8 aQ1 = *(const bf16x8*)&qkv[qoff + 32];

  float mr[4] = {-INFINITY, -INFINITY, -INFINITY, -INFINITY};
  float lr[4] = {0.f, 0.f, 0.f, 0.f};
  f32x4 o[4] = {};
  const int nt = qc + 1;

  for (int kt = 0; kt < nt; ++kt) {
    __syncthreads();  // prior-tile reads done before overwrite
#pragma unroll
    for (int i = 0; i < 2; ++i) {  // stage K: linear dest, pre-swizzled source (rule 21)
      int c = t + i * 256;
      int row = c >> 3, ch = c & 7;
      gload_lds16(qkv + (rowbase + kt * 64 + row) * QKVS + D + hh * 64 +
                      (size_t)((ch ^ (row & 7)) * 8),
                  &sK[c * 8]);
    }
    {  // stage V transposed via ushort2 pairs: thread = (key pair a, dim group d0)
      const int a = t & 31, d0 = (t >> 5) * 8;
      const size_t vrow = (rowbase + kt * 64 + 2 * a) * QKVS + 2 * D + hh * 64 + d0;
      bf16x8 vA = *(const bf16x8*)&qkv[vrow];
      bf16x8 vB = *(const bf16x8*)&qkv[vrow + QKVS];
#pragma unroll
      for (int j = 0; j < 8; ++j) {
        ushort2 w;
        w.x = ((u16*)&vA)[j];
        w.y = ((u16*)&vB)[j];
        *(ushort2*)&sVT[(d0 + j) * 72 + 2 * a] = w;
      }
    }
    __syncthreads();

    // QK^T: S[16q][64k] = 4 key-frags x 2 mfma
    f32x4 s[4];
    __builtin_amdgcn_s_setprio(1);
#pragma unroll
    for (int f = 0; f < 4; ++f) {
      const int krow = f * 16 + l15;
      bf16x8 bk0 = *(const bf16x8*)&sK[krow * 64 + ((g ^ (krow & 7)) * 8)];
      bf16x8 bk1 = *(const bf16x8*)&sK[krow * 64 + (((g + 4) ^ (krow & 7)) * 8)];
      f32x4 z = {};
      z = __builtin_amdgcn_mfma_f32_16x16x32_bf16(aQ0, bk0, z, 0, 0, 0);
      s[f] = __builtin_amdgcn_mfma_f32_16x16x32_bf16(aQ1, bk1, z, 0, 0, 0);
    }
    __builtin_amdgcn_s_setprio(0);

    // online softmax per q-row (rows in (g,i); keys in (f,l15))
    float p[4][4], scl[4];
    const bool diag = (kt == qc);  // only the diagonal tile needs causal masking
#pragma unroll
    for (int i = 0; i < 4; ++i) {
      float v0 = s[0][i], v1 = s[1][i], v2 = s[2][i], v3 = s[3][i];
      if (diag) {
        const int qrow = q0 + wid * 16 + g * 4 + i;
        const int kb = kt * 64 + l15;
        v0 = (kb <= qrow) ? v0 : -INFINITY;
        v1 = (kb + 16 <= qrow) ? v1 : -INFINITY;
        v2 = (kb + 32 <= qrow) ? v2 : -INFINITY;
        v3 = (kb + 48 <= qrow) ? v3 : -INFINITY;
      }
      float mt = fmaxf(fmaxf(v0, v1), fmaxf(v2, v3));
#pragma unroll
      for (int off = 1; off < 16; off <<= 1) mt = fmaxf(mt, __shfl_xor(mt, off));
      const float mn = fmaxf(mr[i], mt);
      const float sc = __expf(mr[i] - mn);
      p[0][i] = __expf(v0 - mn); p[1][i] = __expf(v1 - mn);
      p[2][i] = __expf(v2 - mn); p[3][i] = __expf(v3 - mn);
      float rs = p[0][i] + p[1][i] + p[2][i] + p[3][i];
#pragma unroll
      for (int off = 1; off < 16; off <<= 1) rs += __shfl_xor(rs, off);
      lr[i] = lr[i] * sc + rs;
      mr[i] = mn;
      scl[i] = sc;
    }
#pragma unroll
    for (int n = 0; n < 4; ++n) {
      o[n][0] *= scl[0]; o[n][1] *= scl[1]; o[n][2] *= scl[2]; o[n][3] *= scl[3];
    }
#pragma unroll
    for (int f = 0; f < 4; ++f)  // P -> per-wave LDS (C-layout scatter, A-layout gather)
#pragma unroll
      for (int i = 0; i < 4; ++i)
        sPw[(g * 4 + i) * 72 + f * 16 + l15] = f2bf(p[f][i]);

    // PV: O[16q][64d] += P[16q][64k] V[64k][64d]
    __builtin_amdgcn_s_setprio(1);
#pragma unroll
    for (int kb = 0; kb < 2; ++kb) {
      bf16x8 pa = *(const bf16x8*)&sPw[l15 * 72 + kb * 32 + g * 8];
#pragma unroll
      for (int n = 0; n < 4; ++n) {
        bf16x8 bv = *(const bf16x8*)&sVT[(n * 16 + l15) * 72 + kb * 32 + g * 8];
        o[n] = __builtin_amdgcn_mfma_f32_16x16x32_bf16(pa, bv, o[n], 0, 0, 0);
      }
    }
    __builtin_amdgcn_s_setprio(0);
  }

  float inv[4] = {1.0f / lr[0], 1.0f / lr[1], 1.0f / lr[2], 1.0f / lr[3]};
#pragma unroll
  for (int n = 0; n < 4; ++n)
#pragma unroll
    for (int i = 0; i < 4; ++i)
      ctx[(rowbase + q0 + wid * 16 + g * 4 + i) * D + hh * 64 + n * 16 + l15] =
          f2bf(o[n][i] * inv[i]);
}

// ---------------- host orchestration ----------------
extern "C" void kernel_launch(void* const* d_in, const int* in_sizes, int n_in,
                              void* d_out, int out_size, void* d_ws, size_t ws_size,
                              hipStream_t stream) {
  (void)in_sizes; (void)n_in; (void)out_size;
  const int* x = (const int*)d_in[0];
  const float* tok = (const float*)d_in[1];
  const float* pos = (const float*)d_in[2];
  const float* Wq = (const float*)d_in[3];
  const float* bq = (const float*)d_in[4];
  const float* Wk = (const float*)d_in[5];
  const float* bk = (const float*)d_in[6];
  const float* Wv = (const float*)d_in[7];
  const float* bv = (const float*)d_in[8];
  const float* Wo = (const float*)d_in[9];
  const float* bo = (const float*)d_in[10];
  const float* ln1_g = (const float*)d_in[11];
  const float* ln1_b = (const float*)d_in[12];
  const float* ln2_g = (const float*)d_in[13];
  const float* ln2_b = (const float*)d_in[14];
  const float* W1 = (const float*)d_in[15];
  const float* b1 = (const float*)d_in[16];
  const float* W2 = (const float*)d_in[17];
  const float* b2 = (const float*)d_in[18];
  const float* lnf_g = (const float*)d_in[19];
  const float* lnf_b = (const float*)d_in[20];

  char* ws = (char*)d_ws;
  size_t off = 0;
  auto alloc = [&](size_t bytes) {
    void* p = ws + off;
    off += (bytes + 255) & ~(size_t)255;
    return p;
  };
  u16* wqkvT = (u16*)alloc((size_t)L * 3 * D * D * 2);  // [layer][3D][D] fused
  u16* woT   = (u16*)alloc((size_t)L * D * D * 2);
  u16* w1T   = (u16*)alloc((size_t)L * D * FF * 2);     // [layer][FF][D]
  u16* w2T   = (u16*)alloc((size_t)L * FF * D * 2);     // [layer][D][FF]
  u16* tokT  = (u16*)alloc((size_t)V * D * 2);
  float* bQKV = (float*)alloc((size_t)L * QKVS * 4);    // fused qkv bias
  float* h   = (float*)alloc((size_t)M * D * 4);
  u16* x2    = (u16*)alloc((size_t)M * D * 2);
  u16* qkv   = (u16*)alloc((size_t)M * QKVS * 2);
  u16* ctx   = (u16*)alloc((size_t)M * D * 2);
  u16* ffb   = (u16*)alloc((size_t)M * FF * 2);
  u16* hf    = (u16*)alloc((size_t)M * D * 2);
  if (off > ws_size) return;  // insufficient workspace -> loud validation failure

  const dim3 tb(32, 8);
  transpose_qkvo<<<dim3(D / 32, D / 32, 4 * L), tb, 0, stream>>>(Wq, Wk, Wv, Wo, wqkvT, woT);
  transpose_cvt<<<dim3(FF / 32, D / 32, L), tb, 0, stream>>>(W1, w1T, D, FF);
  transpose_cvt<<<dim3(D / 32, FF / 32, L), tb, 0, stream>>>(W2, w2T, FF, D);
  convert_bf16<<<2048, 256, 0, stream>>>(tok, tokT, (long)V * D / 4);
  fuse_bias<<<dim3(QKVS / 256, L), 256, 0, stream>>>(bq, bk, bv, bQKV);

  embed_kernel<<<M, 256, 0, stream>>>(x, tok, pos, h);

  for (int l = 0; l < L; ++l) {
    layernorm_kernel<<<M / 4, 256, 0, stream>>>(h, ln1_g + (size_t)l * D, ln1_b + (size_t)l * D, x2);
    gemm_qkv<<<dim3(M / 128, QKVS / 64), 256, 0, stream>>>(
        x2, wqkvT + (size_t)l * 3 * D * D, bQKV + (size_t)l * QKVS, qkv);
    attn_mfma<<<dim3(T / 64, Bsz * H), 256, 0, stream>>>(qkv, ctx);
    gemm_proj<<<dim3(M / 64, D / 64), 256, 0, stream>>>(ctx, woT + (size_t)l * D * D,
                                                        bo + (size_t)l * D, h);
    layernorm_kernel<<<M / 4, 256, 0, stream>>>(h, ln2_g + (size_t)l * D, ln2_b + (size_t)l * D, x2);
    gemm_ff1<<<dim3(M / 128, FF / 64), 256, 0, stream>>>(x2, w1T + (size_t)l * D * FF,
                                                         b1 + (size_t)l * FF, ffb);
    gemm_ff2<<<dim3(M / 64, D / 64), 256, 0, stream>>>(ffb, w2T + (size_t)l * FF * D,
                                                       b2 + (size_t)l * D, h);
  }

  layernorm_kernel<<<M / 4, 256, 0, stream>>>(h, lnf_g, lnf_b, hf);
  gemm_lm<<<dim3(16, 393), 256, 0, stream>>>(hf, tokT, (float*)d_out);
}